// Round 19
// baseline (822.013 us; speedup 1.0000x reference)
//
#include <hip/hip_runtime.h>
#include <hip/hip_bf16.h>

#define D_ 128

typedef __attribute__((ext_vector_type(8))) short short8;
typedef __attribute__((ext_vector_type(4))) float f32x4;
typedef __attribute__((address_space(1))) const unsigned int g_u32;
typedef __attribute__((address_space(3))) unsigned int l_u32;

static __device__ __forceinline__ float lrelu(float x) { return x > 0.f ? x : 0.01f * x; }
static __device__ __forceinline__ short f2bf(float f) {
    __hip_bfloat16 h = __float2bfloat16(f);
    return *reinterpret_cast<short*>(&h);
}
static __device__ __forceinline__ unsigned short f2bfu(float f) {
    __hip_bfloat16 h = __float2bfloat16(f);
    return *reinterpret_cast<unsigned short*>(&h);
}
// pack 4 floats -> 4 fp8 e4m3 (OCP on gfx950) via HW cvt
static __device__ __forceinline__ unsigned int f2fp8x4(float a, float b, float c, float d) {
    unsigned int p = __builtin_amdgcn_cvt_pk_fp8_f32(a, b, 0, 0);       // low 16
    p = __builtin_amdgcn_cvt_pk_fp8_f32(c, d, p, 1);                    // high 16
    return p;
}

// ---------------- fused zero: out_nodes + sumn/sume + cnt ----------------
__global__ void zero_bufs(float* __restrict__ out_nodes, long n4_nodes,
                          float* __restrict__ sums,           // sumn..sume contiguous: 512 float4
                          int* __restrict__ cnt, int n4_cnt) {
    long i = (long)blockIdx.x * 256 + threadIdx.x;
    if (i < n4_nodes) { ((f32x4*)out_nodes)[i] = (f32x4){0.f, 0.f, 0.f, 0.f}; return; }
    long j = i - n4_nodes;
    if (j < 512) { ((f32x4*)sums)[j] = (f32x4){0.f, 0.f, 0.f, 0.f}; return; }
    j -= 512;
    if (j < n4_cnt) ((int4*)cnt)[j] = make_int4(0, 0, 0, 0);
}

// ---------------- fused prep (weights/nodes/glbs) + edges cvt+sum+hist ----------------
__global__ void prep_all(const float* __restrict__ Wn0, const float* __restrict__ We0,
                         const float* __restrict__ Wn1, const float* __restrict__ We1,
                         const float* __restrict__ bn0, const float* __restrict__ be0,
                         const float* __restrict__ bn1, const float* __restrict__ be1,
                         const float* __restrict__ nodes, const float* __restrict__ glbs,
                         long nq, int prep_blocks,
                         unsigned char* __restrict__ W0F, short* __restrict__ W1T,
                         float* __restrict__ b0c, float* __restrict__ b1c,
                         unsigned char* __restrict__ nodes_f8, unsigned char* __restrict__ glbs_f8,
                         const float* __restrict__ edges, const int* __restrict__ n_edge,
                         const int* __restrict__ receivers, int* __restrict__ hist,
                         int G, int E_, float* __restrict__ sume,
                         unsigned char* __restrict__ edges_f8) {
    if ((int)blockIdx.x < prep_blocks) {
        long i = (long)blockIdx.x * 256 + threadIdx.x;
        if (i < nq) {  // nodes: 4 f32 -> 4 fp8
            float4 v = ((const float4*)nodes)[i];
            ((unsigned int*)nodes_f8)[i] = f2fp8x4(v.x, v.y, v.z, v.w);
            return;
        }
        long j = i - nq;
        if (j < 512 * 128) {  // W0F: n (0..511), k4 (0..127)
            int n = (int)(j >> 7), k4 = (int)(j & 127);
            float v0, v1, v2, v3;
            if (n < 256) {
                v0 = Wn0[(k4 * 4 + 0) * 256 + n]; v1 = Wn0[(k4 * 4 + 1) * 256 + n];
                v2 = Wn0[(k4 * 4 + 2) * 256 + n]; v3 = Wn0[(k4 * 4 + 3) * 256 + n];
            } else {
                int m = n - 256;
                v0 = We0[(k4 * 4 + 0) * 256 + m]; v1 = We0[(k4 * 4 + 1) * 256 + m];
                v2 = We0[(k4 * 4 + 2) * 256 + m]; v3 = We0[(k4 * 4 + 3) * 256 + m];
            }
            ((unsigned int*)W0F)[n * 128 + k4] = f2fp8x4(v0, v1, v2, v3);
            return;
        }
        j -= 512 * 128;
        if (j < 256 * 256) {
            int n = (int)(j >> 8), k = (int)(j & 255);
            float v = (n < 128) ? Wn1[k * 128 + n] : We1[k * 128 + (n - 128)];
            W1T[j] = f2bf(v);
            return;
        }
        j -= 256 * 256;
        if (j < 512) { b0c[j] = (j < 256) ? bn0[j] : be0[j - 256]; return; }
        if (j < 768) { int t = (int)j - 512; b1c[t] = (t < 128) ? bn1[t] : be1[t - 128]; return; }
        j -= 768;
        if (j < 256) {
            const float* g4 = glbs + j * 4;
            ((unsigned int*)glbs_f8)[j] = f2fp8x4(g4[0], g4[1], g4[2], g4[3]);
        }
        return;
    }

    // ---- edges: fp8 cvt + per-graph sums + receiver histogram ----
    const int bb = (int)blockIdx.x - prep_blocks;
    int c4 = threadIdx.x & 31;
    int rl = threadIdx.x >> 5;
    int r0 = bb * 512 + rl;
    int rend = min(E_, bb * 512 + 512);
    int s_ = 0;
    int cu0 = 0x7fffffff, cu1 = 0x7fffffff, cu2 = 0x7fffffff, cu3 = 0x7fffffff;
    int cu4 = 0x7fffffff, cu5 = 0x7fffffff, cu6 = 0x7fffffff, cu7 = 0x7fffffff;
#define CUF(I, CU) if (I < G) { s_ += n_edge[I]; CU = s_; }
    CUF(0, cu0) CUF(1, cu1) CUF(2, cu2) CUF(3, cu3)
    CUF(4, cu4) CUF(5, cu5) CUF(6, cu6) CUF(7, cu7)
#undef CUF
    f32x4 acc = {0.f, 0.f, 0.f, 0.f};
    int accg = -1;
    for (int r = r0; r < rend; r += 8) {
        int g = (r >= cu0) + (r >= cu1) + (r >= cu2) + (r >= cu3)
              + (r >= cu4) + (r >= cu5) + (r >= cu6) + (r >= cu7);
        if (g != accg) {
            if (accg >= 0) {
#pragma unroll
                for (int j = 0; j < 4; j++) atomicAdd(&sume[accg * D_ + c4 * 4 + j], acc[j]);
            }
            acc = (f32x4){0.f, 0.f, 0.f, 0.f}; accg = g;
        }
        const float4 v = *(const float4*)(edges + (long)r * D_ + c4 * 4);
        acc[0] += v.x; acc[1] += v.y; acc[2] += v.z; acc[3] += v.w;
        ((unsigned int*)edges_f8)[(long)r * 32 + c4] = f2fp8x4(v.x, v.y, v.z, v.w);
        if (c4 == 0) atomicAdd(&hist[receivers[r]], 1);
    }
    if (accg >= 0) {
#pragma unroll
        for (int j = 0; j < 4; j++) atomicAdd(&sume[accg * D_ + c4 * 4 + j], acc[j]);
    }
}

// ---------------- counting sort: scan + place ----------------
__global__ void scan_counts(const int* __restrict__ cnt, int N_, int* __restrict__ off) {
    __shared__ int part[256];
    int t = threadIdx.x;
    int chunk = (N_ + 255) / 256;
    int b = t * chunk, e = min(N_, b + chunk);
    int s = 0;
    for (int i = b; i < e; i++) s += cnt[i];
    part[t] = s;
    __syncthreads();
    for (int o = 1; o < 256; o <<= 1) {
        int v = (t >= o) ? part[t - o] : 0;
        __syncthreads();
        part[t] += v;
        __syncthreads();
    }
    int run = part[t] - s;
    for (int i = b; i < e; i++) { off[i] = run; run += cnt[i]; }
}

__global__ void place_edges(const int* __restrict__ receivers, int E_,
                            int* __restrict__ off, int* __restrict__ sorted) {
    int e = blockIdx.x * 256 + threadIdx.x;
    if (e < E_) {
        int p = atomicAdd(&off[receivers[e]], 1);
        sorted[p] = e;
    }
}

// ---------------- per-graph node sums ----------------
__global__ void seg_sum(const float* __restrict__ src, const int* __restrict__ counts,
                        int G, int rows, int chunk, float* __restrict__ out) {
    int c4 = threadIdx.x & 31;
    int rl = threadIdx.x >> 5;
    int r0 = blockIdx.x * chunk + rl;
    int rend = min(rows, blockIdx.x * chunk + chunk);
    int s_ = 0;
    int cu0 = 0x7fffffff, cu1 = 0x7fffffff, cu2 = 0x7fffffff, cu3 = 0x7fffffff;
    int cu4 = 0x7fffffff, cu5 = 0x7fffffff, cu6 = 0x7fffffff, cu7 = 0x7fffffff;
#define CUF(I, CU) if (I < G) { s_ += counts[I]; CU = s_; }
    CUF(0, cu0) CUF(1, cu1) CUF(2, cu2) CUF(3, cu3)
    CUF(4, cu4) CUF(5, cu5) CUF(6, cu6) CUF(7, cu7)
#undef CUF
    f32x4 acc = {0.f, 0.f, 0.f, 0.f};
    int accg = -1;
    for (int r = r0; r < rend; r += 8) {
        int g = (r >= cu0) + (r >= cu1) + (r >= cu2) + (r >= cu3)
              + (r >= cu4) + (r >= cu5) + (r >= cu6) + (r >= cu7);
        if (g != accg) {
            if (accg >= 0) {
#pragma unroll
                for (int j = 0; j < 4; j++) atomicAdd(&out[accg * D_ + c4 * 4 + j], acc[j]);
            }
            acc = (f32x4){0.f, 0.f, 0.f, 0.f}; accg = g;
        }
        const float4 v = *(const float4*)(src + (long)r * D_ + c4 * 4);
        acc[0] += v.x; acc[1] += v.y; acc[2] += v.z; acc[3] += v.w;
    }
    if (accg >= 0) {
#pragma unroll
        for (int j = 0; j < 4; j++) atomicAdd(&out[accg * D_ + c4 * 4 + j], acc[j]);
    }
}

// ---------------- global-feature MLP (384 threads: 3 input GEMVs in parallel) ----------------
__global__ void global_mlp(const float* __restrict__ glbs, const float* __restrict__ sumn,
                           const float* __restrict__ sume,
                           const float* __restrict__ Wg, const float* __restrict__ bg,
                           const float* __restrict__ Wgn, const float* __restrict__ bgn,
                           const float* __restrict__ Wge, const float* __restrict__ bge,
                           const float* __restrict__ Wf, const float* __restrict__ bfv,
                           float* __restrict__ outg) {
    __shared__ float s_tmp[384];
    int r = blockIdx.x;
    int c   = threadIdx.x & 127;
    int grp = threadIdx.x >> 7;   // 0..2
    const float* src = (grp == 0) ? glbs : (grp == 1) ? sumn : sume;
    const float* W   = (grp == 0) ? Wg   : (grp == 1) ? Wgn  : Wge;
    const float* b   = (grp == 0) ? bg   : (grp == 1) ? bgn  : bge;
    float a = 0.f;
    for (int k = 0; k < 128; k++) a += src[r * 128 + k] * W[k * 128 + c];
    s_tmp[grp * 128 + c] = lrelu(a + b[c]);
    __syncthreads();
    if (threadIdx.x < 128) {
        float a2 = 0.f;
        for (int k = 0; k < 384; k++) a2 += s_tmp[k] * Wf[k * 128 + c];
        outg[r * 128 + c] = lrelu(a2 + bfv[c]);
    }
}

// ---------------- fused per-edge MLP: 64-edge tile, 512 thr = 8 waves, 2 blocks/CU ----------------
// SINGLE-PASS fp8 L1 (wave: 64 rows x 64 cols, acc[4][4] = 64 AGPR, R18-proven spill-free),
// bf16 L2; s_setprio(1) around MFMA clusters (independent-block regime, T5).
__launch_bounds__(512, 4)
__global__ void edge_mlp(const unsigned char* __restrict__ nodes_f8,
                         const unsigned char* __restrict__ edges_f8,
                         const unsigned char* __restrict__ glbs_f8,
                         const int* __restrict__ senders, const int* __restrict__ receivers,
                         const int* __restrict__ sorted_eid,
                         const int* __restrict__ n_edge, int G, int NT,
                         const unsigned char* __restrict__ W0F, const short* __restrict__ W1T,
                         const float* __restrict__ b0c, const float* __restrict__ b1c,
                         float* __restrict__ out_nodes, float* __restrict__ out_edges) {
    __shared__ __align__(16) char sX[65536];
    __shared__ int s_eid[64], s_recv[64], s_snd[64], s_gid[64];
    __shared__ int sh_rprev, sh_rnext;

    const int tid  = threadIdx.x;
    const int lane = tid & 63;
    const int wid  = tid >> 6;   // 0..7
    const int wn   = wid;        // layer-1 col-slice id (64 cols each)
    const int l15  = lane & 15;
    const int lk   = lane >> 4;  // 0..3

    const int tile = blockIdx.x;
    const int base = tile * 64;
    const int Etot = NT * 64;

    int s_ = 0;
    int cu0 = 0x7fffffff, cu1 = 0x7fffffff, cu2 = 0x7fffffff, cu3 = 0x7fffffff;
    int cu4 = 0x7fffffff, cu5 = 0x7fffffff, cu6 = 0x7fffffff, cu7 = 0x7fffffff;
#define CUF(I, CU) if (I < G) { s_ += n_edge[I]; CU = s_; }
    CUF(0, cu0) CUF(1, cu1) CUF(2, cu2) CUF(3, cu3)
    CUF(4, cu4) CUF(5, cu5) CUF(6, cu6) CUF(7, cu7)
#undef CUF

    if (tid < 64) {
        int eid = sorted_eid[base + tid];
        s_eid[tid]  = eid;
        s_snd[tid]  = senders[eid];
        s_recv[tid] = receivers[eid];
        s_gid[tid]  = (eid >= cu0) + (eid >= cu1) + (eid >= cu2) + (eid >= cu3)
                    + (eid >= cu4) + (eid >= cu5) + (eid >= cu6) + (eid >= cu7);
    }
    if (tid == 64) sh_rprev = (base > 0) ? receivers[sorted_eid[base - 1]] : -1;
    if (tid == 65) sh_rnext = (base + 64 < Etot) ? receivers[sorted_eid[base + 64]] : -1;
    __syncthreads();

    // ---- stage X (fp8) into [0,32K): 2 rows per glds, 4 glds per wave ----
#pragma unroll
    for (int r = 0; r < 4; ++r) {
        const int p   = r * 8 + wid;         // wave-uniform row pair 0..31
        const int row = 2 * p + (lane >> 5);
        const int src = (lane >> 3) & 3;
        const int sub = lane & 7;
        char* dst = sX + p * 1024;           // linear dst; HW adds lane*16
        const unsigned char* bp = (src == 0) ? nodes_f8 + (long)s_snd[row] * 128
                                 : (src == 1) ? nodes_f8 + (long)s_recv[row] * 128
                                 : (src == 2) ? edges_f8 + (long)s_eid[row] * 128
                                              : glbs_f8 + (long)s_gid[row] * 128;
        __builtin_amdgcn_global_load_lds((g_u32*)(bp + ((sub ^ (row & 7)) << 4)), (l_u32*)dst, 16, 0, 0);
    }
    __syncthreads();

    // ---- layer 1 (fp8, single pass): X[64x512] @ W0F[512x512]; wave = 64 rows x 64 cols ----
    f32x4 acc[4][4];
#pragma unroll
    for (int mt = 0; mt < 4; ++mt)
#pragma unroll
        for (int nt = 0; nt < 4; ++nt) acc[mt][nt] = (f32x4){0.f, 0.f, 0.f, 0.f};

    __builtin_amdgcn_s_setprio(1);
#pragma unroll
    for (int t = 0; t < 16; ++t) {
        long bfr[4];
#pragma unroll
        for (int nt = 0; nt < 4; ++nt) {
            int n = wn * 64 + nt * 16 + l15;
            bfr[nt] = *(const long*)(W0F + (long)n * 512 + t * 32 + lk * 8);
        }
#pragma unroll
        for (int mt = 0; mt < 4; ++mt) {
            int row = mt * 16 + l15;
            int g16 = (t * 2 + (lk >> 1)) ^ (row & 7);
            long af = *(const long*)(sX + row * 512 + (g16 << 4) + ((lk & 1) << 3));
#pragma unroll
            for (int nt = 0; nt < 4; ++nt)
                acc[mt][nt] = __builtin_amdgcn_mfma_f32_16x16x32_fp8_fp8(af, bfr[nt], acc[mt][nt], 0, 0, 0);
        }
    }
    __builtin_amdgcn_s_setprio(0);
    __syncthreads();   // all X reads complete; [0,64K) free for H

    // bias + leaky + bf16 -> H [64 rows][1024 B] @ [0,64K), byte-16 XOR swizzle
#pragma unroll
    for (int nt = 0; nt < 4; ++nt) {
        int col = wn * 64 + nt * 16 + l15;
        float bias = b0c[col];
#pragma unroll
        for (int mt = 0; mt < 4; ++mt) {
#pragma unroll
            for (int q = 0; q < 4; ++q) {
                int row = mt * 16 + lk * 4 + q;
                float v = lrelu(acc[mt][nt][q] + bias);
                *(short*)(sX + row * 1024 + ((col * 2) ^ ((row & 7) << 4))) = f2bf(v);
            }
        }
    }
    __syncthreads();   // H fully written

    // ---- layer 2 (bf16): waves 0-3 node-msg, waves 4-7 edge-update; 32 cols each ----
    const int branch = wid >> 2;
    const int qn     = wid & 3;
    f32x4 acc2[4][2];
#pragma unroll
    for (int mt = 0; mt < 4; ++mt)
#pragma unroll
        for (int nt = 0; nt < 2; ++nt) acc2[mt][nt] = (f32x4){0.f, 0.f, 0.f, 0.f};

    __builtin_amdgcn_s_setprio(1);
#pragma unroll
    for (int kt = 0; kt < 8; ++kt) {
        short8 bfr2[2];
#pragma unroll
        for (int nt = 0; nt < 2; ++nt) {
            int ncl = qn * 32 + nt * 16 + l15;
            bfr2[nt] = *(const short8*)(W1T + (long)(branch * 128 + ncl) * 256 + kt * 32 + lk * 8);
        }
#pragma unroll
        for (int mt = 0; mt < 4; ++mt) {
            int row = mt * 16 + l15;
            int kbyte = (branch * 256 + kt * 32 + lk * 8) * 2;
            short8 af = *(const short8*)(sX + row * 1024 + (kbyte ^ ((row & 7) << 4)));
#pragma unroll
            for (int nt = 0; nt < 2; ++nt)
                acc2[mt][nt] = __builtin_amdgcn_mfma_f32_16x16x32_bf16(af, bfr2[nt], acc2[mt][nt], 0, 0, 0);
        }
    }
    __builtin_amdgcn_s_setprio(0);
    __syncthreads();  // H reads done; [0,32K) becomes f32 msg buffer

    // epilogue: msgs -> LDS @[0,32K) (swizzled), edge-updates -> global
#pragma unroll
    for (int nt = 0; nt < 2; ++nt) {
        int ncl = qn * 32 + nt * 16 + l15;
        float bias = b1c[branch * 128 + ncl];
#pragma unroll
        for (int mt = 0; mt < 4; ++mt) {
#pragma unroll
            for (int q = 0; q < 4; ++q) {
                int row = mt * 16 + lk * 4 + q;
                float v = lrelu(acc2[mt][nt][q] + bias);
                if (branch == 0) {
                    *(float*)(sX + row * 512 + ((ncl * 4) ^ (((row >> 2) & 3) << 6))) = v;
                } else {
                    out_edges[(long)s_eid[row] * D_ + ncl] = v;
                }
            }
        }
    }
    __syncthreads();

    // segmented reduction: exclusive segments -> plain store; boundary -> atomicAdd
    {
        int c  = tid & 127;
        int qr = tid >> 7;        // 0..3 -> rows [qr*16, qr*16+16)
        int r0 = qr * 16, r1 = r0 + 16;
        float v[16];
#pragma unroll
        for (int i = 0; i < 16; ++i) {
            int r = r0 + i;
            v[i] = *(const float*)(sX + r * 512 + ((c * 4) ^ (((r >> 2) & 3) << 6)));
        }
        int leftr = (r0 == 0) ? sh_rprev : s_recv[r0 - 1];
        float acc_s = 0.f;
        int cur = s_recv[r0];
        bool shl = (leftr == cur);
#pragma unroll
        for (int i = 0; i < 16; ++i) {
            int rc = s_recv[r0 + i];
            if (rc != cur) {
                if (shl) atomicAdd(&out_nodes[(long)cur * D_ + c], acc_s);
                else     out_nodes[(long)cur * D_ + c] = acc_s;
                shl = false; acc_s = 0.f; cur = rc;
            }
            acc_s += v[i];
        }
        int rightr = (r1 == 64) ? sh_rnext : s_recv[r1];
        if (shl || rightr == cur) atomicAdd(&out_nodes[(long)cur * D_ + c], acc_s);
        else                      out_nodes[(long)cur * D_ + c] = acc_s;
    }
}

extern "C" void kernel_launch(void* const* d_in, const int* in_sizes, int n_in,
                              void* d_out, int out_size, void* d_ws, size_t ws_size,
                              hipStream_t stream) {
    const float* nodes     = (const float*)d_in[0];
    const float* edges     = (const float*)d_in[1];
    const float* glbs      = (const float*)d_in[2];
    const int*   senders   = (const int*)d_in[3];
    const int*   receivers = (const int*)d_in[4];
    const int*   n_node    = (const int*)d_in[5];
    const int*   n_edge    = (const int*)d_in[6];
    const float* Wn0 = (const float*)d_in[7];
    const float* bn0 = (const float*)d_in[8];
    const float* Wn1 = (const float*)d_in[9];
    const float* bn1 = (const float*)d_in[10];
    const float* We0 = (const float*)d_in[11];
    const float* be0 = (const float*)d_in[12];
    const float* We1 = (const float*)d_in[13];
    const float* be1 = (const float*)d_in[14];
    const float* Wgn = (const float*)d_in[15];
    const float* bgn = (const float*)d_in[16];
    const float* Wge = (const float*)d_in[17];
    const float* bge = (const float*)d_in[18];
    const float* Wg  = (const float*)d_in[19];
    const float* bg  = (const float*)d_in[20];
    const float* Wf  = (const float*)d_in[21];
    const float* bfv = (const float*)d_in[22];

    const int N = in_sizes[0] / 128;
    const int E = in_sizes[1] / 128;
    const int G = in_sizes[2] / 128;
    const int NT = E / 64;   // 6250 tiles of 64 edges

    char* ws = (char*)d_ws;
    unsigned char* W0F = (unsigned char*)(ws);           // 512*512 = 262144 B
    short* W1T  = (short*)(ws + 262144);                 // 131072 B
    float* b0c  = (float*)(ws + 393216);                 // 2048 B
    float* b1c  = (float*)(ws + 395264);                 // 1024 B
    float* sumn = (float*)(ws + 396288);                 // 4096 B
    float* sume = (float*)(ws + 400384);                 // 4096 B (contiguous after sumn)
    unsigned char* glbs_f8  = (unsigned char*)(ws + 404480);  // 1024 B
    unsigned char* nodes_f8 = (unsigned char*)(ws + 405504);  // N*128 B
    char* ws2 = ws + 405504 + (size_t)N * 128;
    int* cnt        = (int*)(ws2);                       // N*4 (rounded to int4 below)
    int* tmp_off    = (int*)(ws2 + (size_t)((N + 3) & ~3) * 4);
    int* sorted_eid = (int*)(ws2 + (size_t)((N + 3) & ~3) * 8);
    unsigned char* edges_f8 = (unsigned char*)(ws2 + (size_t)((N + 3) & ~3) * 8 + (size_t)E * 4);

    float* out_nodes = (float*)d_out;
    float* out_edges = out_nodes + (long)N * 128;
    float* out_glb   = out_edges + (long)E * 128;

    // fused zero: out_nodes (N*128 f32) + sumn/sume (2048 f32) + cnt (N int, padded to x4)
    const long n4_nodes = (long)N * 32;
    const int  n4_cnt   = (N + 3) / 4;
    const long zero_items = n4_nodes + 512 + n4_cnt;
    zero_bufs<<<(int)((zero_items + 255) / 256), 256, 0, stream>>>(
        out_nodes, n4_nodes, sumn, cnt, n4_cnt);

    // fused prep + edges cvt/sum/hist
    const long nq = (long)N * 32;
    const long prep_items  = nq + 512 * 128 + 256 * 256 + 768 + 256;
    const int  prep_blocks = (int)((prep_items + 255) / 256);
    const int  conv_blocks = (E + 511) / 512;
    prep_all<<<prep_blocks + conv_blocks, 256, 0, stream>>>(
        Wn0, We0, Wn1, We1, bn0, be0, bn1, be1, nodes, glbs, nq, prep_blocks,
        W0F, W1T, b0c, b1c, nodes_f8, glbs_f8,
        edges, n_edge, receivers, cnt, G, E, sume, edges_f8);

    scan_counts<<<1, 256, 0, stream>>>(cnt, N, tmp_off);
    place_edges<<<(E + 255) / 256, 256, 0, stream>>>(receivers, E, tmp_off, sorted_eid);

    edge_mlp<<<NT, 512, 0, stream>>>(nodes_f8, edges_f8, glbs_f8, senders, receivers,
                                     sorted_eid, n_edge, G, NT,
                                     W0F, W1T, b0c, b1c, out_nodes, out_edges);

    seg_sum<<<(N + 127) / 128, 256, 0, stream>>>(nodes, n_node, G, N, 128, sumn);

    global_mlp<<<G, 384, 0, stream>>>(glbs, sumn, sume, Wg, bg, Wgn, bgn, Wge, bge, Wf, bfv,
                                      out_glb);
}

// Round 20
// 786.558 us; speedup vs baseline: 1.0451x; 1.0451x over previous
//
#include <hip/hip_runtime.h>
#include <hip/hip_bf16.h>

#define D_ 128

typedef __attribute__((ext_vector_type(8))) short short8;
typedef __attribute__((ext_vector_type(4))) float f32x4;
typedef __attribute__((address_space(1))) const unsigned int g_u32;
typedef __attribute__((address_space(3))) unsigned int l_u32;

static __device__ __forceinline__ float lrelu(float x) { return x > 0.f ? x : 0.01f * x; }
static __device__ __forceinline__ short f2bf(float f) {
    __hip_bfloat16 h = __float2bfloat16(f);
    return *reinterpret_cast<short*>(&h);
}
static __device__ __forceinline__ unsigned short f2bfu(float f) {
    __hip_bfloat16 h = __float2bfloat16(f);
    return *reinterpret_cast<unsigned short*>(&h);
}
// pack 4 floats -> 4 fp8 e4m3 (OCP on gfx950) via HW cvt
static __device__ __forceinline__ unsigned int f2fp8x4(float a, float b, float c, float d) {
    unsigned int p = __builtin_amdgcn_cvt_pk_fp8_f32(a, b, 0, 0);       // low 16
    p = __builtin_amdgcn_cvt_pk_fp8_f32(c, d, p, 1);                    // high 16
    return p;
}

// ---------------- prep: W0 -> fp8 [n][k], W1 -> bf16 [n][k], biases, nodes/glbs -> fp8 ----------------
__global__ void prep(const float* __restrict__ Wn0, const float* __restrict__ We0,
                     const float* __restrict__ Wn1, const float* __restrict__ We1,
                     const float* __restrict__ bn0, const float* __restrict__ be0,
                     const float* __restrict__ bn1, const float* __restrict__ be1,
                     const float* __restrict__ nodes, const float* __restrict__ glbs,
                     long nq,
                     unsigned char* __restrict__ W0F, short* __restrict__ W1T,
                     float* __restrict__ b0c, float* __restrict__ b1c,
                     unsigned char* __restrict__ nodes_f8, unsigned char* __restrict__ glbs_f8) {
    long i = (long)blockIdx.x * 256 + threadIdx.x;
    if (i < nq) {  // nodes: 4 f32 -> 4 fp8
        float4 v = ((const float4*)nodes)[i];
        ((unsigned int*)nodes_f8)[i] = f2fp8x4(v.x, v.y, v.z, v.w);
        return;
    }
    long j = i - nq;
    if (j < 512 * 128) {  // W0F: n (0..511), k4 (0..127)
        int n = (int)(j >> 7), k4 = (int)(j & 127);
        float v0, v1, v2, v3;
        if (n < 256) {
            v0 = Wn0[(k4 * 4 + 0) * 256 + n]; v1 = Wn0[(k4 * 4 + 1) * 256 + n];
            v2 = Wn0[(k4 * 4 + 2) * 256 + n]; v3 = Wn0[(k4 * 4 + 3) * 256 + n];
        } else {
            int m = n - 256;
            v0 = We0[(k4 * 4 + 0) * 256 + m]; v1 = We0[(k4 * 4 + 1) * 256 + m];
            v2 = We0[(k4 * 4 + 2) * 256 + m]; v3 = We0[(k4 * 4 + 3) * 256 + m];
        }
        ((unsigned int*)W0F)[n * 128 + k4] = f2fp8x4(v0, v1, v2, v3);
        return;
    }
    j -= 512 * 128;
    if (j < 256 * 256) {
        int n = (int)(j >> 8), k = (int)(j & 255);
        float v = (n < 128) ? Wn1[k * 128 + n] : We1[k * 128 + (n - 128)];
        W1T[j] = f2bf(v);
        return;
    }
    j -= 256 * 256;
    if (j < 512) { b0c[j] = (j < 256) ? bn0[j] : be0[j - 256]; return; }
    if (j < 768) { int t = (int)j - 512; b1c[t] = (t < 128) ? bn1[t] : be1[t - 128]; return; }
    j -= 768;
    if (j < 256) {  // glbs: 4 per thread
        const float* g4 = glbs + j * 4;
        ((unsigned int*)glbs_f8)[j] = f2fp8x4(g4[0], g4[1], g4[2], g4[3]);
    }
}

// ---------------- counting sort: scan (1024 threads) + place ----------------
__global__ void scan_counts(const int* __restrict__ cnt, int N_, int* __restrict__ off) {
    __shared__ int part[1024];
    int t = threadIdx.x;
    int chunk = (N_ + 1023) / 1024;
    int b = t * chunk, e = min(N_, b + chunk);
    int s = 0;
    for (int i = b; i < e; i++) s += cnt[i];
    part[t] = s;
    __syncthreads();
    for (int o = 1; o < 1024; o <<= 1) {
        int v = (t >= o) ? part[t - o] : 0;
        __syncthreads();
        part[t] += v;
        __syncthreads();
    }
    int run = part[t] - s;  // exclusive prefix
    for (int i = b; i < e; i++) { off[i] = run; run += cnt[i]; }
}

__global__ void place_edges(const int* __restrict__ receivers, int E_,
                            int* __restrict__ off, int* __restrict__ sorted) {
    int e = blockIdx.x * 256 + threadIdx.x;
    if (e < E_) {
        int p = atomicAdd(&off[receivers[e]], 1);
        sorted[p] = e;
    }
}

// ---------------- per-graph node sums ----------------
__global__ void seg_sum(const float* __restrict__ src, const int* __restrict__ counts,
                        int G, int rows, int chunk, float* __restrict__ out) {
    int c4 = threadIdx.x & 31;
    int rl = threadIdx.x >> 5;
    int r0 = blockIdx.x * chunk + rl;
    int rend = min(rows, blockIdx.x * chunk + chunk);
    int s_ = 0;
    int cu0 = 0x7fffffff, cu1 = 0x7fffffff, cu2 = 0x7fffffff, cu3 = 0x7fffffff;
    int cu4 = 0x7fffffff, cu5 = 0x7fffffff, cu6 = 0x7fffffff, cu7 = 0x7fffffff;
#define CUF(I, CU) if (I < G) { s_ += counts[I]; CU = s_; }
    CUF(0, cu0) CUF(1, cu1) CUF(2, cu2) CUF(3, cu3)
    CUF(4, cu4) CUF(5, cu5) CUF(6, cu6) CUF(7, cu7)
#undef CUF
    f32x4 acc = {0.f, 0.f, 0.f, 0.f};
    int accg = -1;
    for (int r = r0; r < rend; r += 8) {
        int g = (r >= cu0) + (r >= cu1) + (r >= cu2) + (r >= cu3)
              + (r >= cu4) + (r >= cu5) + (r >= cu6) + (r >= cu7);
        if (g != accg) {
            if (accg >= 0) {
#pragma unroll
                for (int j = 0; j < 4; j++) atomicAdd(&out[accg * D_ + c4 * 4 + j], acc[j]);
            }
            acc = (f32x4){0.f, 0.f, 0.f, 0.f}; accg = g;
        }
        const float4 v = *(const float4*)(src + (long)r * D_ + c4 * 4);
        acc[0] += v.x; acc[1] += v.y; acc[2] += v.z; acc[3] += v.w;
    }
    if (accg >= 0) {
#pragma unroll
        for (int j = 0; j < 4; j++) atomicAdd(&out[accg * D_ + c4 * 4 + j], acc[j]);
    }
}

// ---------------- edges: f32 -> fp8 cvt FUSED with per-graph edge sums AND receiver histogram ----------------
__global__ void conv_sum_edges(const float* __restrict__ src, const int* __restrict__ counts,
                               const int* __restrict__ receivers, int* __restrict__ hist,
                               int G, int rows, int chunk,
                               float* __restrict__ out, unsigned char* __restrict__ dst_f8) {
    int c4 = threadIdx.x & 31;
    int rl = threadIdx.x >> 5;
    int r0 = blockIdx.x * chunk + rl;
    int rend = min(rows, blockIdx.x * chunk + chunk);
    int s_ = 0;
    int cu0 = 0x7fffffff, cu1 = 0x7fffffff, cu2 = 0x7fffffff, cu3 = 0x7fffffff;
    int cu4 = 0x7fffffff, cu5 = 0x7fffffff, cu6 = 0x7fffffff, cu7 = 0x7fffffff;
#define CUF(I, CU) if (I < G) { s_ += counts[I]; CU = s_; }
    CUF(0, cu0) CUF(1, cu1) CUF(2, cu2) CUF(3, cu3)
    CUF(4, cu4) CUF(5, cu5) CUF(6, cu6) CUF(7, cu7)
#undef CUF
    f32x4 acc = {0.f, 0.f, 0.f, 0.f};
    int accg = -1;
    for (int r = r0; r < rend; r += 8) {
        int g = (r >= cu0) + (r >= cu1) + (r >= cu2) + (r >= cu3)
              + (r >= cu4) + (r >= cu5) + (r >= cu6) + (r >= cu7);
        if (g != accg) {
            if (accg >= 0) {
#pragma unroll
                for (int j = 0; j < 4; j++) atomicAdd(&out[accg * D_ + c4 * 4 + j], acc[j]);
            }
            acc = (f32x4){0.f, 0.f, 0.f, 0.f}; accg = g;
        }
        const float4 v = *(const float4*)(src + (long)r * D_ + c4 * 4);
        acc[0] += v.x; acc[1] += v.y; acc[2] += v.z; acc[3] += v.w;
        ((unsigned int*)dst_f8)[(long)r * 32 + c4] = f2fp8x4(v.x, v.y, v.z, v.w);
        if (c4 == 0) atomicAdd(&hist[receivers[r]], 1);   // fused histogram
    }
    if (accg >= 0) {
#pragma unroll
        for (int j = 0; j < 4; j++) atomicAdd(&out[accg * D_ + c4 * 4 + j], acc[j]);
    }
}

// ---------------- global-feature MLP (384 threads: 3 input GEMVs in parallel) ----------------
__global__ void global_mlp(const float* __restrict__ glbs, const float* __restrict__ sumn,
                           const float* __restrict__ sume,
                           const float* __restrict__ Wg, const float* __restrict__ bg,
                           const float* __restrict__ Wgn, const float* __restrict__ bgn,
                           const float* __restrict__ Wge, const float* __restrict__ bge,
                           const float* __restrict__ Wf, const float* __restrict__ bfv,
                           float* __restrict__ outg) {
    __shared__ float s_tmp[384];
    int r = blockIdx.x;
    int c   = threadIdx.x & 127;
    int grp = threadIdx.x >> 7;   // 0..2
    const float* src = (grp == 0) ? glbs : (grp == 1) ? sumn : sume;
    const float* W   = (grp == 0) ? Wg   : (grp == 1) ? Wgn  : Wge;
    const float* b   = (grp == 0) ? bg   : (grp == 1) ? bgn  : bge;
    float a = 0.f;
    for (int k = 0; k < 128; k++) a += src[r * 128 + k] * W[k * 128 + c];
    s_tmp[grp * 128 + c] = lrelu(a + b[c]);
    __syncthreads();
    if (threadIdx.x < 128) {
        float a2 = 0.f;
        for (int k = 0; k < 384; k++) a2 += s_tmp[k] * Wf[k * 128 + c];
        outg[r * 128 + c] = lrelu(a2 + bfv[c]);
    }
}

// ---------------- fused per-edge MLP: 64-edge tile, 512 thr = 8 waves, 2 blocks/CU ----------------
// SINGLE-PASS fp8 L1 (wave: 64 rows x 64 cols, acc[4][4] = 64 AGPR; arch+acc = 128 exact,
// R18-proven spill-free shape), bf16 L2.
// LDS: [0,32K) X fp8 -> after barrier H [64 rows][512 bf16] = [0,64K) -> msg f32 @ [0,32K).
__launch_bounds__(512, 4)
__global__ void edge_mlp(const unsigned char* __restrict__ nodes_f8,
                         const unsigned char* __restrict__ edges_f8,
                         const unsigned char* __restrict__ glbs_f8,
                         const int* __restrict__ senders, const int* __restrict__ receivers,
                         const int* __restrict__ sorted_eid,
                         const int* __restrict__ n_edge, int G, int NT,
                         const unsigned char* __restrict__ W0F, const short* __restrict__ W1T,
                         const float* __restrict__ b0c, const float* __restrict__ b1c,
                         float* __restrict__ out_nodes, float* __restrict__ out_edges) {
    __shared__ __align__(16) char sX[65536];
    __shared__ int s_eid[64], s_recv[64], s_snd[64], s_gid[64];
    __shared__ int sh_rprev, sh_rnext;

    const int tid  = threadIdx.x;
    const int lane = tid & 63;
    const int wid  = tid >> 6;   // 0..7
    const int wn   = wid;        // layer-1 col-slice id (64 cols each)
    const int l15  = lane & 15;
    const int lk   = lane >> 4;  // 0..3

    const int tile = blockIdx.x;
    const int base = tile * 64;
    const int Etot = NT * 64;

    int s_ = 0;
    int cu0 = 0x7fffffff, cu1 = 0x7fffffff, cu2 = 0x7fffffff, cu3 = 0x7fffffff;
    int cu4 = 0x7fffffff, cu5 = 0x7fffffff, cu6 = 0x7fffffff, cu7 = 0x7fffffff;
#define CUF(I, CU) if (I < G) { s_ += n_edge[I]; CU = s_; }
    CUF(0, cu0) CUF(1, cu1) CUF(2, cu2) CUF(3, cu3)
    CUF(4, cu4) CUF(5, cu5) CUF(6, cu6) CUF(7, cu7)
#undef CUF

    if (tid < 64) {
        int eid = sorted_eid[base + tid];
        s_eid[tid]  = eid;
        s_snd[tid]  = senders[eid];
        s_recv[tid] = receivers[eid];
        s_gid[tid]  = (eid >= cu0) + (eid >= cu1) + (eid >= cu2) + (eid >= cu3)
                    + (eid >= cu4) + (eid >= cu5) + (eid >= cu6) + (eid >= cu7);
    }
    if (tid == 64) sh_rprev = (base > 0) ? receivers[sorted_eid[base - 1]] : -1;
    if (tid == 65) sh_rnext = (base + 64 < Etot) ? receivers[sorted_eid[base + 64]] : -1;
    __syncthreads();

    // ---- stage X (fp8) into [0,32K): 2 rows per glds, 4 glds per wave ----
#pragma unroll
    for (int r = 0; r < 4; ++r) {
        const int p   = r * 8 + wid;         // wave-uniform row pair 0..31
        const int row = 2 * p + (lane >> 5);
        const int src = (lane >> 3) & 3;
        const int sub = lane & 7;
        char* dst = sX + p * 1024;           // linear dst; HW adds lane*16
        const unsigned char* bp = (src == 0) ? nodes_f8 + (long)s_snd[row] * 128
                                 : (src == 1) ? nodes_f8 + (long)s_recv[row] * 128
                                 : (src == 2) ? edges_f8 + (long)s_eid[row] * 128
                                              : glbs_f8 + (long)s_gid[row] * 128;
        __builtin_amdgcn_global_load_lds((g_u32*)(bp + ((sub ^ (row & 7)) << 4)), (l_u32*)dst, 16, 0, 0);
    }
    __syncthreads();

    // ---- layer 1 (fp8, SINGLE PASS): X[64x512] @ W0F[512x512]; wave = 64 rows x 64 cols ----
    f32x4 acc[4][4];
#pragma unroll
    for (int mt = 0; mt < 4; ++mt)
#pragma unroll
        for (int nt = 0; nt < 4; ++nt) acc[mt][nt] = (f32x4){0.f, 0.f, 0.f, 0.f};

#pragma unroll
    for (int t = 0; t < 16; ++t) {
        long bfr[4];
#pragma unroll
        for (int nt = 0; nt < 4; ++nt) {
            int n = wn * 64 + nt * 16 + l15;
            bfr[nt] = *(const long*)(W0F + (long)n * 512 + t * 32 + lk * 8);
        }
#pragma unroll
        for (int mt = 0; mt < 4; ++mt) {
            int row = mt * 16 + l15;
            int g16 = (t * 2 + (lk >> 1)) ^ (row & 7);
            long af = *(const long*)(sX + row * 512 + (g16 << 4) + ((lk & 1) << 3));
#pragma unroll
            for (int nt = 0; nt < 4; ++nt)
                acc[mt][nt] = __builtin_amdgcn_mfma_f32_16x16x32_fp8_fp8(af, bfr[nt], acc[mt][nt], 0, 0, 0);
        }
    }
    __syncthreads();   // all X reads complete; [0,64K) free for H

    // bias + leaky + bf16 -> H [64 rows][1024 B] @ [0,64K), byte-16 XOR swizzle
#pragma unroll
    for (int nt = 0; nt < 4; ++nt) {
        int col = wn * 64 + nt * 16 + l15;
        float bias = b0c[col];
#pragma unroll
        for (int mt = 0; mt < 4; ++mt) {
#pragma unroll
            for (int q = 0; q < 4; ++q) {
                int row = mt * 16 + lk * 4 + q;
                float v = lrelu(acc[mt][nt][q] + bias);
                *(short*)(sX + row * 1024 + ((col * 2) ^ ((row & 7) << 4))) = f2bf(v);
            }
        }
    }
    __syncthreads();   // H fully written

    // ---- layer 2 (bf16): waves 0-3 node-msg, waves 4-7 edge-update; 32 cols each ----
    const int branch = wid >> 2;
    const int qn     = wid & 3;
    f32x4 acc2[4][2];
#pragma unroll
    for (int mt = 0; mt < 4; ++mt)
#pragma unroll
        for (int nt = 0; nt < 2; ++nt) acc2[mt][nt] = (f32x4){0.f, 0.f, 0.f, 0.f};

#pragma unroll
    for (int kt = 0; kt < 8; ++kt) {
        short8 bfr2[2];
#pragma unroll
        for (int nt = 0; nt < 2; ++nt) {
            int ncl = qn * 32 + nt * 16 + l15;
            bfr2[nt] = *(const short8*)(W1T + (long)(branch * 128 + ncl) * 256 + kt * 32 + lk * 8);
        }
#pragma unroll
        for (int mt = 0; mt < 4; ++mt) {
            int row = mt * 16 + l15;
            int kbyte = (branch * 256 + kt * 32 + lk * 8) * 2;
            short8 af = *(const short8*)(sX + row * 1024 + (kbyte ^ ((row & 7) << 4)));
#pragma unroll
            for (int nt = 0; nt < 2; ++nt)
                acc2[mt][nt] = __builtin_amdgcn_mfma_f32_16x16x32_bf16(af, bfr2[nt], acc2[mt][nt], 0, 0, 0);
        }
    }
    __syncthreads();  // H reads done; [0,32K) becomes f32 msg buffer

    // epilogue: msgs -> LDS @[0,32K) (swizzled), edge-updates -> global
#pragma unroll
    for (int nt = 0; nt < 2; ++nt) {
        int ncl = qn * 32 + nt * 16 + l15;
        float bias = b1c[branch * 128 + ncl];
#pragma unroll
        for (int mt = 0; mt < 4; ++mt) {
#pragma unroll
            for (int q = 0; q < 4; ++q) {
                int row = mt * 16 + lk * 4 + q;
                float v = lrelu(acc2[mt][nt][q] + bias);
                if (branch == 0) {
                    *(float*)(sX + row * 512 + ((ncl * 4) ^ (((row >> 2) & 3) << 6))) = v;
                } else {
                    out_edges[(long)s_eid[row] * D_ + ncl] = v;
                }
            }
        }
    }
    __syncthreads();

    // segmented reduction: exclusive segments -> plain store; boundary -> atomicAdd
    {
        int c  = tid & 127;
        int qr = tid >> 7;        // 0..3 -> rows [qr*16, qr*16+16)
        int r0 = qr * 16, r1 = r0 + 16;
        float v[16];
#pragma unroll
        for (int i = 0; i < 16; ++i) {
            int r = r0 + i;
            v[i] = *(const float*)(sX + r * 512 + ((c * 4) ^ (((r >> 2) & 3) << 6)));
        }
        int leftr = (r0 == 0) ? sh_rprev : s_recv[r0 - 1];
        float acc_s = 0.f;
        int cur = s_recv[r0];
        bool shl = (leftr == cur);    // current segment extends left of my range
#pragma unroll
        for (int i = 0; i < 16; ++i) {
            int rc = s_recv[r0 + i];
            if (rc != cur) {
                if (shl) atomicAdd(&out_nodes[(long)cur * D_ + c], acc_s);
                else     out_nodes[(long)cur * D_ + c] = acc_s;
                shl = false; acc_s = 0.f; cur = rc;
            }
            acc_s += v[i];
        }
        int rightr = (r1 == 64) ? sh_rnext : s_recv[r1];
        if (shl || rightr == cur) atomicAdd(&out_nodes[(long)cur * D_ + c], acc_s);
        else                      out_nodes[(long)cur * D_ + c] = acc_s;
    }
}

extern "C" void kernel_launch(void* const* d_in, const int* in_sizes, int n_in,
                              void* d_out, int out_size, void* d_ws, size_t ws_size,
                              hipStream_t stream) {
    const float* nodes     = (const float*)d_in[0];
    const float* edges     = (const float*)d_in[1];
    const float* glbs      = (const float*)d_in[2];
    const int*   senders   = (const int*)d_in[3];
    const int*   receivers = (const int*)d_in[4];
    const int*   n_node    = (const int*)d_in[5];
    const int*   n_edge    = (const int*)d_in[6];
    const float* Wn0 = (const float*)d_in[7];
    const float* bn0 = (const float*)d_in[8];
    const float* Wn1 = (const float*)d_in[9];
    const float* bn1 = (const float*)d_in[10];
    const float* We0 = (const float*)d_in[11];
    const float* be0 = (const float*)d_in[12];
    const float* We1 = (const float*)d_in[13];
    const float* be1 = (const float*)d_in[14];
    const float* Wgn = (const float*)d_in[15];
    const float* bgn = (const float*)d_in[16];
    const float* Wge = (const float*)d_in[17];
    const float* bge = (const float*)d_in[18];
    const float* Wg  = (const float*)d_in[19];
    const float* bg  = (const float*)d_in[20];
    const float* Wf  = (const float*)d_in[21];
    const float* bfv = (const float*)d_in[22];

    const int N = in_sizes[0] / 128;
    const int E = in_sizes[1] / 128;
    const int G = in_sizes[2] / 128;
    const int NT = E / 64;   // 6250 tiles of 64 edges

    char* ws = (char*)d_ws;
    unsigned char* W0F = (unsigned char*)(ws);           // 512*512 = 262144 B
    short* W1T  = (short*)(ws + 262144);                 // 131072 B
    float* b0c  = (float*)(ws + 393216);                 // 2048 B
    float* b1c  = (float*)(ws + 395264);                 // 1024 B
    float* sumn = (float*)(ws + 396288);                 // 4096 B
    float* sume = (float*)(ws + 400384);                 // 4096 B
    unsigned char* glbs_f8  = (unsigned char*)(ws + 404480);  // 1024 B
    unsigned char* nodes_f8 = (unsigned char*)(ws + 405504);  // N*128 B
    char* ws2 = ws + 405504 + (size_t)N * 128;
    int* cnt        = (int*)(ws2);                       // N*4
    int* tmp_off    = (int*)(ws2 + (size_t)N * 4);       // N*4
    int* sorted_eid = (int*)(ws2 + (size_t)N * 8);       // E*4
    unsigned char* edges_f8 = (unsigned char*)(ws2 + (size_t)N * 8 + (size_t)E * 4);  // E*128 B

    float* out_nodes = (float*)d_out;
    float* out_edges = out_nodes + (long)N * 128;
    float* out_glb   = out_edges + (long)E * 128;

    hipMemsetAsync(out_nodes, 0, (size_t)N * 128 * sizeof(float), stream);
    hipMemsetAsync(sumn, 0, 8192, stream);
    hipMemsetAsync(cnt, 0, (size_t)N * 4, stream);

    const long nq = (long)N * 32;  // float4 count for nodes
    const long prep_items = nq + 512 * 128 + 256 * 256 + 768 + 256;
    prep<<<(int)((prep_items + 255) / 256), 256, 0, stream>>>(
        Wn0, We0, Wn1, We1, bn0, be0, bn1, be1, nodes, glbs, nq,
        W0F, W1T, b0c, b1c, nodes_f8, glbs_f8);

    // edges: fp8 cvt + per-graph sums + receiver histogram (fused)
    conv_sum_edges<<<(E + 511) / 512, 256, 0, stream>>>(edges, n_edge, receivers, cnt,
                                                        G, E, 512, sume, edges_f8);

    scan_counts<<<1, 1024, 0, stream>>>(cnt, N, tmp_off);
    place_edges<<<(E + 255) / 256, 256, 0, stream>>>(receivers, E, tmp_off, sorted_eid);

    edge_mlp<<<NT, 512, 0, stream>>>(nodes_f8, edges_f8, glbs_f8, senders, receivers,
                                     sorted_eid, n_edge, G, NT,
                                     W0F, W1T, b0c, b1c, out_nodes, out_edges);

    seg_sum<<<(N + 127) / 128, 256, 0, stream>>>(nodes, n_node, G, N, 128, sumn);

    global_mlp<<<G, 384, 0, stream>>>(glbs, sumn, sume, Wg, bg, Wgn, bgn, Wge, bge, Wf, bfv,
                                      out_glb);
}